// Round 17
// baseline (334.869 us; speedup 1.0000x reference)
//
#include <hip/hip_runtime.h>

// Quantized 3x3 conv, stride 1, pad 1 (MI355X / gfx950):
//   x: [32,64,112,112] fp32 -> uint4-range [0,15]
//   w: [128,64,3,3]    fp32 -> int4-range  [-8,7]
//   out: [32,128,112,112] fp32 (integer-exact)
//
// R17: PERSISTENT WORK-QUEUE PIPELINE. Prep (22 us, BW-floor) used to run
// fully BEFORE conv (63 us); but conv consumes images in prep's production
// order, so the two can overlap. One persistent kernel, 768 co-resident
// blocks (launch_bounds(256,4) + 21.9 KB LDS guarantee >=4 blocks/CU
// capacity => all resident => no deadlock), static stride over items:
//   items 0..1823    : activation quant (image n, 2 padded rows)
//   items 1824..5407 : conv (one output row x 128 cout, R15 body)
// Gating: act_done[n] (device-scope, agent) counts to 57; prep blocks
// release-add after their stores, conv blocks relaxed-spin then acquire
// fence (cross-XCD L2 non-coherence handled per G16).
// k_init (tiny, prior kernel): weight quant -> fragment-major wq + zero flags.

#define CIN  64
#define HH   112
#define WW   112
#define HW   (HH * WW)
#define COUT 128
#define HP   114
#define WP   114
#define KTOT 576

#define XQ_BYTES (32 * HP * WP * 64)     // 26,615,808
#define WQ_BYTES (COUT * KTOT)           // 73,728
#define NWBLK 288                        // weight quant blocks in k_init

#define NACT   (32 * 57)                 // 1824 activation items (2 rows each)
#define NCONVI (32 * HH)                 // 3584 conv items (1 output row each)
#define NITEMS (NACT + NCONVI)           // 5408
#define GPERS  768                       // persistent blocks (<= guaranteed capacity)

#define ROWB (WP * 64)                   // 7296 B per padded row
#define SLAB_BYTES (3 * ROWB)            // 21,888 B (3 padded rows)
#define SLAB_U16   (SLAB_BYTES / 16)     // 1368 16-byte units

typedef __attribute__((ext_vector_type(4))) int int32x4;

__global__ __launch_bounds__(256) void k_init(const float* __restrict__ w,
                                              char* __restrict__ wq,
                                              int* __restrict__ flags) {
    const int bid = blockIdx.x, tid = threadIdx.x;
    if (bid < NWBLK) {
        // ---- weights, fragment-major: idx = dest byte ----
        // idx = ks*8192 + ct*1024 + ln*16 + j
        // -> cout = ct*16 + (ln&15), c = (ln>>4)*16 + j, kh = ks/3, kw = ks%3
        int idx = bid * 256 + tid;
        int ks  = idx / 8192;
        int r2  = idx % 8192;
        int ct  = r2 / 1024;
        int r3  = r2 % 1024;
        int ln  = r3 / 16;
        int j   = r3 % 16;
        int o   = ct * 16 + (ln & 15);
        int c   = (ln >> 4) * 16 + j;
        int kh  = ks / 3, kw = ks % 3;
        float q = fminf(fmaxf(rintf(w[((o * CIN + c) * 3 + kh) * 3 + kw]), -8.0f), 7.0f);
        wq[idx] = (char)(int)q;
        return;
    }
    // last block: zero the gating flags (published by kernel boundary)
    if (tid < 64) flags[tid] = 0;
}

__global__ __launch_bounds__(256, 4) void k_main(const float* __restrict__ x,
                                                 char* __restrict__ xq,
                                                 const char* __restrict__ wq,
                                                 float* __restrict__ out,
                                                 int* __restrict__ flags) {
    __shared__ char slab[SLAB_BYTES];     // 21,888 B
    const int tid = threadIdx.x;

    for (int item = blockIdx.x; item < NITEMS; item += GPERS) {
        if (item < NACT) {
            // ================= activation prep: image n, padded rows 2pr,2pr+1 =================
            const int n  = item / 57;
            const int pr = item % 57;
            const int hp = pr * 2 + (tid >> 7);
            const int wp = tid & 127;
            if (wp < WP) {
                char* dst = xq + (((size_t)n * HP + hp) * WP + wp) * 64;
                int32x4* d4 = (int32x4*)dst;
                if (hp == 0 || hp == HP - 1 || wp == 0 || wp == WP - 1) {
#pragma unroll
                    for (int i = 0; i < 4; ++i) d4[i] = (int32x4)(0);
                } else {
                    const int h = hp - 1, ww = wp - 1;
                    const float* px = x + (((size_t)n * CIN) * HH + h) * WW + ww;
                    unsigned int buf[16];
#pragma unroll
                    for (int cw = 0; cw < 16; ++cw) {
                        unsigned int word = 0;
#pragma unroll
                        for (int j = 0; j < 4; ++j) {
                            float v = px[(size_t)(cw * 4 + j) * HW];
                            float q = fminf(fmaxf(rintf(v), 0.0f), 15.0f);
                            word |= ((unsigned int)(int)q) << (8 * j);
                        }
                        buf[cw] = word;
                    }
#pragma unroll
                    for (int i = 0; i < 4; ++i) {
                        int32x4 v;
                        v.x = (int)buf[i * 4 + 0];
                        v.y = (int)buf[i * 4 + 1];
                        v.z = (int)buf[i * 4 + 2];
                        v.w = (int)buf[i * 4 + 3];
                        d4[i] = v;
                    }
                }
            }
            __syncthreads();   // all waves' stores drained (vmcnt) before publish
            if (tid == 0)
                __hip_atomic_fetch_add(&flags[n], 1, __ATOMIC_RELEASE,
                                       __HIP_MEMORY_SCOPE_AGENT);
        } else {
            // ================= conv: one output row x 128 cout =================
            const int nid = item - NACT;
            const int n   = nid / HH;
            const int h   = nid % HH;

            if (tid == 0) {
                while (__hip_atomic_load(&flags[n], __ATOMIC_RELAXED,
                                         __HIP_MEMORY_SCOPE_AGENT) < 57)
                    __builtin_amdgcn_s_sleep(2);
            }
            __syncthreads();   // broadcast readiness + protect slab from prev item
            __builtin_amdgcn_fence(__ATOMIC_ACQUIRE, "agent");

            // ---- stage: padded rows h..h+2 of xq (contiguous) -> linear memcpy ----
            const char* src = xq + (size_t)n * (HP * ROWB) + (size_t)h * ROWB;
#pragma unroll
            for (int k = 0; k < 6; ++k) {
                const int u = tid + k * 256;
                if (u < SLAB_U16)
                    *(int32x4*)(&slab[u * 16]) = *(const int32x4*)(src + u * 16);
            }
            __syncthreads();

            const int wave = tid >> 6;
            const int lane = tid & 63;
            const int l15  = lane & 15;
            const int lk   = lane >> 4;
            const int Q    = wave;           // cout quarter

            const char* wbase = wq + (Q * 2) * 1024 + lane * 16;

            int32x4 acc[7][2];
#pragma unroll
            for (int i = 0; i < 7; ++i) {
                acc[i][0] = (int32x4)(0);
                acc[i][1] = (int32x4)(0);
            }

            int32x4 b0[2], b1[2], b2[2];
            b0[0] = *(const int32x4*)(wbase);
            b0[1] = *(const int32x4*)(wbase + 1024);
            b1[0] = *(const int32x4*)(wbase + 8192);
            b1[1] = *(const int32x4*)(wbase + 8192 + 1024);

#pragma unroll
            for (int ks = 0; ks < 9; ++ks) {
                const int ksn = (ks + 2 <= 8) ? ks + 2 : 8;
                b2[0] = *(const int32x4*)(wbase + ksn * 8192);
                b2[1] = *(const int32x4*)(wbase + ksn * 8192 + 1024);
                const int kh = ks / 3, kw = ks % 3;
                const char* arow = &slab[((kh * WP) + l15 + kw) * 64 + lk * 16];
                int32x4 af[7];
#pragma unroll
                for (int wt = 0; wt < 7; ++wt)
                    af[wt] = *(const int32x4*)(arow + wt * 1024);
#pragma unroll
                for (int tO = 0; tO < 2; ++tO)
#pragma unroll
                    for (int wt = 0; wt < 7; ++wt)
                        acc[wt][tO] = __builtin_amdgcn_mfma_i32_16x16x64_i8(af[wt], b0[tO], acc[wt][tO], 0, 0, 0);
                b0[0] = b1[0]; b0[1] = b1[1];
                b1[0] = b2[0]; b1[1] = b2[1];
            }

            // ---- epilogue: D col(l15)=cout, row(lk*4+reg)=spatial w ----
#pragma unroll
            for (int wt = 0; wt < 7; ++wt) {
#pragma unroll
                for (int tO = 0; tO < 2; ++tO) {
                    const int co = Q * 32 + tO * 16 + l15;
                    float4 v;
                    v.x = (float)acc[wt][tO][0];
                    v.y = (float)acc[wt][tO][1];
                    v.z = (float)acc[wt][tO][2];
                    v.w = (float)acc[wt][tO][3];
                    *(float4*)(&out[(((size_t)n * COUT + co) * HH + h) * WW + wt * 16 + lk * 4]) = v;
                }
            }
            __syncthreads();   // stores retired per-wave order not needed; protects slab reuse
        }
    }
}

extern "C" void kernel_launch(void* const* d_in, const int* in_sizes, int n_in,
                              void* d_out, int out_size, void* d_ws, size_t ws_size,
                              hipStream_t stream) {
    const float* x = (const float*)d_in[0];
    const float* w = (const float*)d_in[1];
    float* out = (float*)d_out;

    char* xq = (char*)d_ws;
    char* wq = xq + XQ_BYTES;
    int* flags = (int*)(wq + WQ_BYTES);

    hipLaunchKernelGGL(k_init, dim3(NWBLK + 1), dim3(256), 0, stream, w, wq, flags);
    hipLaunchKernelGGL(k_main, dim3(GPERS), dim3(256), 0, stream, x, xq, wq, out, flags);
}

// Round 18
// 86.907 us; speedup vs baseline: 3.8532x; 3.8532x over previous
//
#include <hip/hip_runtime.h>

// Quantized 3x3 conv, stride 1, pad 1 (MI355X / gfx950):
//   x: [32,64,112,112] fp32 -> uint4-range [0,15]
//   w: [128,64,3,3]    fp32 -> int4-range  [-8,7]
//   out: [32,128,112,112] fp32 (integer-exact)
//
// R18 = REVERT to R16 (best measured: 87.14 us; R9 tied at 87.19).
// Session findings baked into this kernel:
//   - split pipeline (prep -> conv) beats all fused variants (R3/R4/R17)
//   - conv stages its 3-row activation slab in LDS via linear memcpy
//     (each xq byte enters a CU once; fixed the 9x L2/L3/HBM re-read that
//     pinned early convs at ~80 us)
//   - fragment-major weights, all 18 B-fragments in registers (72 VGPR),
//     loaded once per block, latency hidden under the slab stage
//   - wt-major loop: per output column, 9 LDS A-reads + 18 MFMA + 2 stores
//   - XCD-bijective block swizzle (3584 = 8*448) for halo L2 reuse
// Structural floor at HIP level: prep ~= 22 us (compulsory x read),
// conv ~= 63 us (serial sum stores 33 + LDS 13 + MFMA 15 + stage 3);
// 10 overlap/structure experiments (R5-R17) all landed at >= 87 us.

#define CIN  64
#define HH   112
#define WW   112
#define HW   (HH * WW)
#define COUT 128
#define HP   114
#define WP   114
#define KTOT 576

#define XQ_BYTES (32 * HP * WP * 64)     // 26,615,808
#define NWBLK 288                        // 288*256 = 73728 weight bytes
#define NXBLK (32 * 57)                  // activation prep blocks (2 rows each)
#define NCONV (32 * HH)                  // 3584 = 8 * 448 (bijective XCD chunking)

#define ROWB (WP * 64)                   // 7296 B per padded row
#define SLAB_BYTES (3 * ROWB)            // 21,888 B (3 padded rows)
#define SLAB_U16   (SLAB_BYTES / 16)     // 1368 16-byte units

typedef __attribute__((ext_vector_type(4))) int int32x4;

__global__ __launch_bounds__(256) void k_prep(const float* __restrict__ x,
                                              const float* __restrict__ w,
                                              char* __restrict__ xq,
                                              char* __restrict__ wq) {
    const int bid = blockIdx.x, tid = threadIdx.x;
    if (bid < NWBLK) {
        // ---- weights, fragment-major: idx = dest byte ----
        // idx = ks*8192 + ct*1024 + ln*16 + j
        // -> cout = ct*16 + (ln&15), c = (ln>>4)*16 + j, kh = ks/3, kw = ks%3
        int idx = bid * 256 + tid;
        int ks  = idx / 8192;
        int r2  = idx % 8192;
        int ct  = r2 / 1024;
        int r3  = r2 % 1024;
        int ln  = r3 / 16;
        int j   = r3 % 16;
        int o   = ct * 16 + (ln & 15);
        int c   = (ln >> 4) * 16 + j;
        int kh  = ks / 3, kw = ks % 3;
        float q = fminf(fmaxf(rintf(w[((o * CIN + c) * 3 + kh) * 3 + kw]), -8.0f), 7.0f);
        wq[idx] = (char)(int)q;
        return;
    }
    // ---- activations: xq[n][hp][wp][c], zero border ----
    const int rid = bid - NWBLK;          // 0..1823
    const int n  = rid / 57;
    const int hp = (rid % 57) * 2 + (tid >> 7);
    const int wp = tid & 127;
    if (wp >= WP) return;
    char* dst = xq + (((size_t)n * HP + hp) * WP + wp) * 64;
    int32x4* d4 = (int32x4*)dst;
    if (hp == 0 || hp == HP - 1 || wp == 0 || wp == WP - 1) {
#pragma unroll
        for (int i = 0; i < 4; ++i) d4[i] = (int32x4)(0);
        return;
    }
    const int h = hp - 1, ww = wp - 1;
    const float* px = x + (((size_t)n * CIN) * HH + h) * WW + ww;
    unsigned int buf[16];
#pragma unroll
    for (int cw = 0; cw < 16; ++cw) {
        unsigned int word = 0;
#pragma unroll
        for (int j = 0; j < 4; ++j) {
            float v = px[(size_t)(cw * 4 + j) * HW];
            float q = fminf(fmaxf(rintf(v), 0.0f), 15.0f);
            word |= ((unsigned int)(int)q) << (8 * j);
        }
        buf[cw] = word;
    }
#pragma unroll
    for (int i = 0; i < 4; ++i) {
        int32x4 v;
        v.x = (int)buf[i * 4 + 0];
        v.y = (int)buf[i * 4 + 1];
        v.z = (int)buf[i * 4 + 2];
        v.w = (int)buf[i * 4 + 3];
        d4[i] = v;
    }
}

__global__ __launch_bounds__(256, 3) void k_conv(const char* __restrict__ xq,
                                                 const char* __restrict__ wq,
                                                 float* __restrict__ out) {
    __shared__ char slab[SLAB_BYTES];     // 21,888 B: padded rows h..h+2

    const int tid = threadIdx.x;
    // XCD chunking (3584 = 8*448, bijective): consecutive nids = consecutive
    // rows of the same image -> halo-row L2/L3 reuse within an XCD.
    const int nid = (blockIdx.x & 7) * (NCONV / 8) + (blockIdx.x >> 3);
    const int n   = nid / HH;
    const int h   = nid % HH;             // output row

    const int wave = tid >> 6;            // 0..3 = cout quarter
    const int lane = tid & 63;
    const int l15  = lane & 15;
    const int lk   = lane >> 4;           // 16-byte k-chunk within 64 channels
    const int Q    = wave;                // cout quarter (32 couts)

    // ---- issue all 18 weight fragment loads first (L2 latency hides
    //      under the slab stage below) ----
    const char* wbase = wq + (Q * 2) * 1024 + lane * 16;
    int32x4 wreg[9][2];
#pragma unroll
    for (int ks = 0; ks < 9; ++ks) {
        wreg[ks][0] = *(const int32x4*)(wbase + ks * 8192);
        wreg[ks][1] = *(const int32x4*)(wbase + ks * 8192 + 1024);
    }

    // ---- stage: padded rows h..h+2 of xq are CONTIGUOUS -> linear memcpy ----
    const char* src = xq + (size_t)n * (HP * ROWB) + (size_t)h * ROWB;
#pragma unroll
    for (int k = 0; k < 6; ++k) {
        const int u = tid + k * 256;
        if (u < SLAB_U16)
            *(int32x4*)(&slab[u * 16]) = *(const int32x4*)(src + u * 16);
    }
    __syncthreads();

    float* obase = out + (((size_t)n * COUT + Q * 32 + l15) * HH + h) * WW + lk * 4;

    // ---- wt-major: compute one w-column's 2 tiles, store immediately ----
#pragma unroll
    for (int wt = 0; wt < 7; ++wt) {
        int32x4 af[9];
#pragma unroll
        for (int ks = 0; ks < 9; ++ks) {
            const int kh = ks / 3, kw = ks % 3;
            af[ks] = *(const int32x4*)(&slab[((kh * WP) + wt * 16 + l15 + kw) * 64 + lk * 16]);
        }
        int32x4 a0 = (int32x4)(0);
        int32x4 a1 = (int32x4)(0);
#pragma unroll
        for (int ks = 0; ks < 9; ++ks) {
            a0 = __builtin_amdgcn_mfma_i32_16x16x64_i8(af[ks], wreg[ks][0], a0, 0, 0, 0);
            a1 = __builtin_amdgcn_mfma_i32_16x16x64_i8(af[ks], wreg[ks][1], a1, 0, 0, 0);
        }
        float4 v0, v1;
        v0.x = (float)a0[0]; v0.y = (float)a0[1]; v0.z = (float)a0[2]; v0.w = (float)a0[3];
        v1.x = (float)a1[0]; v1.y = (float)a1[1]; v1.z = (float)a1[2]; v1.w = (float)a1[3];
        *(float4*)(obase + wt * 16)            = v0;   // cout = Q*32 + l15
        *(float4*)(obase + 16 * HW + wt * 16)  = v1;   // cout = Q*32 + 16 + l15
    }
}

extern "C" void kernel_launch(void* const* d_in, const int* in_sizes, int n_in,
                              void* d_out, int out_size, void* d_ws, size_t ws_size,
                              hipStream_t stream) {
    const float* x = (const float*)d_in[0];
    const float* w = (const float*)d_in[1];
    float* out = (float*)d_out;

    char* xq = (char*)d_ws;
    char* wq = xq + XQ_BYTES;

    hipLaunchKernelGGL(k_prep, dim3(NWBLK + NXBLK), dim3(256), 0, stream, x, w, xq, wq);
    hipLaunchKernelGGL(k_conv, dim3(NCONV), dim3(256), 0, stream, xq, wq, out);
}